// Round 7
// baseline (323.866 us; speedup 1.0000x reference)
//
#include <hip/hip_runtime.h>
#include <math.h>

// Problem constants
#define BATCH 8
#define WAY 5
#define NQ 75
#define NSAMP 80
#define NP 9
#define CCH 640
#define KLEN 192
#define NIMG (BATCH*NSAMP*NP)   // 5760
#define NGRP (NIMG/4)           // 1440 image-groups (4 imgs each)
#define AS 200                  // LDS row stride (bf16 elems) for A tiles
#define NTILES 20               // 640/32 n-tiles
#define NKS 12                  // 192/16 k-steps
#define NFRAG (NTILES*NKS*64)   // 15360 lane-fragments per plane
#define PBLK 256                // persistent conv blocks
#define QKS 20                  // 640/32 k-steps for sim MFMA

typedef short bf16x8 __attribute__((ext_vector_type(8)));
typedef float f32x16 __attribute__((ext_vector_type(16)));
typedef float f32x4  __attribute__((ext_vector_type(4)));

__device__ __forceinline__ void split_bf16(float x, short& hi, short& lo) {
    unsigned xb = __float_as_uint(x);
    hi = (short)(xb >> 16);
    float hf = __uint_as_float(xb & 0xFFFF0000u);
    float r = x - hf;
    lo = (short)(__float_as_uint(r) >> 16);
}

// ---------------------------------------------------------------------------
// Prep: split conv_w (640x192 fp32) into packed bf16 hi/lo B-fragments.
// Fragment f = nt*12+ks, lane l, elem j: w[nt*32+(l&31)][ks*16+(l>>5)*8+j].
__global__ __launch_bounds__(256) void prep_w_pack(
    const float* __restrict__ w, short* __restrict__ w_hi, short* __restrict__ w_lo)
{
    int f = blockIdx.x * 256 + threadIdx.x;   // float4 index, < 30720
    if (f < CCH * KLEN / 4) {
        int c  = f / 48;
        int kq = f - c * 48;                  // k = kq*4
        int nt = c >> 5;
        int ks = kq >> 2;
        int lane = (c & 31) | (((kq >> 1) & 1) << 5);
        int j = (kq & 1) << 2;
        float4 v = ((const float4*)w)[f];
        short h0, h1, h2, h3, l0, l1, l2, l3;
        split_bf16(v.x, h0, l0);
        split_bf16(v.y, h1, l1);
        split_bf16(v.z, h2, l2);
        split_bf16(v.w, h3, l3);
        size_t dst = ((size_t)(nt * NKS + ks) * 64 + lane) * 8 + j;
        *(short4*)(w_hi + dst) = make_short4(h0, h1, h2, h3);
        *(short4*)(w_lo + dst) = make_short4(l0, l1, l2, l3);
    }
}

// ---------------------------------------------------------------------------
// GEMM inner loop (phase-templated). Wave owns tiles tau = 5*wv + j:
// nt = tau>>1, Mt = tau&1. ks-outer: A read once per ks, reused over 3 nt.
// B prefetch ring distance 2.
template<int PH>
__device__ __forceinline__ void gemm_loop(
    const short* __restrict__ Ah, const short* __restrict__ Al,
    const bf16x8* __restrict__ BH, const bf16x8* __restrict__ BL,
    int abase, f32x16 acc[5])
{
    bf16x8 rh[2][3], rl[2][3];
#pragma unroll
    for (int s = 0; s < 2; s++)
#pragma unroll
        for (int r = 0; r < 3; r++) {
            rh[s][r] = BH[(r * NKS + s) * 64];
            rl[s][r] = BL[(r * NKS + s) * 64];
        }
#pragma unroll
    for (int ks = 0; ks < NKS; ks++) {
        const int s = ks & 1;
        bf16x8 aH0 = *(const bf16x8*)&Ah[abase + ks * 16];
        bf16x8 aL0 = *(const bf16x8*)&Al[abase + ks * 16];
        bf16x8 aH1 = *(const bf16x8*)&Ah[abase + 32 * AS + ks * 16];
        bf16x8 aL1 = *(const bf16x8*)&Al[abase + 32 * AS + ks * 16];
        bf16x8 ch[3], cl[3];
#pragma unroll
        for (int r = 0; r < 3; r++) { ch[r] = rh[s][r]; cl[r] = rl[s][r]; }
        if (ks + 2 < NKS) {
#pragma unroll
            for (int r = 0; r < 3; r++) {
                rh[s][r] = BH[(r * NKS + ks + 2) * 64];
                rl[s][r] = BL[(r * NKS + ks + 2) * 64];
            }
        }
#pragma unroll
        for (int j = 0; j < 5; j++) {
            const int mt  = (j + PH) & 1;
            const int rel = (j + PH) >> 1;
            bf16x8 ah = (mt == 0) ? aH0 : aH1;
            bf16x8 al = (mt == 0) ? aL0 : aL1;
            acc[j] = __builtin_amdgcn_mfma_f32_32x32x16_bf16(ah, ch[rel], acc[j], 0, 0, 0);
            acc[j] = __builtin_amdgcn_mfma_f32_32x32x16_bf16(al, ch[rel], acc[j], 0, 0, 0);
            acc[j] = __builtin_amdgcn_mfma_f32_32x32x16_bf16(ah, cl[rel], acc[j], 0, 0, 0);
        }
    }
}

// ---------------------------------------------------------------------------
// Kernel 1 (persistent, 256 blocks): each block loops over image-groups
// g = bid + 256k. Pipeline: x for the NEXT group is loaded into registers
// during the current group's K-loop; split->LDS happens right after the
// K-loop barrier, epilogue barriers make it visible for the next K-loop.
// Output: featn as bf16 hi/lo planes [NIMG][640].
__global__ __launch_bounds__(512, 2) void conv_mfma(
    const float* __restrict__ x,      // [NIMG,3,32,32]
    const short* __restrict__ w_hi,   // packed B-fragments
    const short* __restrict__ w_lo,
    short* __restrict__ fh,           // [NIMG][640] bf16 hi
    short* __restrict__ fl)           // [NIMG][640] bf16 lo
{
    __shared__ short Ah[64 * AS];             // 25.6 KB
    __shared__ short Al[64 * AS];             // 25.6 KB
    __shared__ float ssq_part[8][64];
    __shared__ float inv_s[64];
    __shared__ float pooled_s[4 * CCH];       // 10.2 KB
    __shared__ float rn_part[8];
    __shared__ float invc_s[4];

    const int t = threadIdx.x;
    const int b0 = blockIdx.x;

    // Per-thread invariant staging indices: f = t + i*512 -> (row,k0)
    int soff[6];
#pragma unroll
    for (int i = 0; i < 6; i++) {
        int f = t + i * 512;
        int img = f / 768;
        int rem = f - img * 768;
        int ci = rem >> 8;
        int rem2 = rem & 255;
        int h = rem2 >> 3;
        int w4 = (rem2 & 7) << 2;
        int s = ((h >> 3) << 2) + (w4 >> 3);
        int k0 = (ci << 6) + ((h & 7) << 3) + (w4 & 7);
        soff[i] = ((img << 4) + s) * AS + k0;
    }

    const int wv = t >> 6;
    const int l  = t & 63;
    const int ln = l & 31;
    const int hh = l >> 5;
    const int ph = wv & 1;
    const int ntBase = (5 * wv) >> 1;
    const bf16x8* BH = (const bf16x8*)w_hi + (size_t)ntBase * (NKS * 64) + l;
    const bf16x8* BL = (const bf16x8*)w_lo + (size_t)ntBase * (NKS * 64) + l;
    const int abase = ln * AS + hh * 8;
    const float4* xbase = (const float4*)x;

    // Prologue: stage group b0, then issue prefetch for b0+256.
    float4 xr[6];
#pragma unroll
    for (int i = 0; i < 6; i++) xr[i] = xbase[(size_t)b0 * 3072 + t + i * 512];
#pragma unroll
    for (int i = 0; i < 6; i++) {
        short h0, h1, h2, h3, l0, l1, l2, l3;
        split_bf16(xr[i].x, h0, l0);
        split_bf16(xr[i].y, h1, l1);
        split_bf16(xr[i].z, h2, l2);
        split_bf16(xr[i].w, h3, l3);
        *(short4*)&Ah[soff[i]] = make_short4(h0, h1, h2, h3);
        *(short4*)&Al[soff[i]] = make_short4(l0, l1, l2, l3);
    }
    if (b0 + PBLK < NGRP) {
#pragma unroll
        for (int i = 0; i < 6; i++)
            xr[i] = xbase[(size_t)(b0 + PBLK) * 3072 + t + i * 512];
    }
    __syncthreads();

#pragma unroll 1
    for (int g = b0; g < NGRP; g += PBLK) {
        f32x16 acc[5];
#pragma unroll
        for (int j = 0; j < 5; j++)
#pragma unroll
            for (int r = 0; r < 16; r++) acc[j][r] = 0.f;

        if (ph == 0) gemm_loop<0>(Ah, Al, BH, BL, abase, acc);
        else         gemm_loop<1>(Ah, Al, BH, BL, abase, acc);

        __syncthreads();   // all waves done reading A-LDS

        // Stage NEXT group into A-LDS; issue prefetch for the one after.
        if (g + PBLK < NGRP) {
#pragma unroll
            for (int i = 0; i < 6; i++) {
                short h0, h1, h2, h3, l0, l1, l2, l3;
                split_bf16(xr[i].x, h0, l0);
                split_bf16(xr[i].y, h1, l1);
                split_bf16(xr[i].z, h2, l2);
                split_bf16(xr[i].w, h3, l3);
                *(short4*)&Ah[soff[i]] = make_short4(h0, h1, h2, h3);
                *(short4*)&Al[soff[i]] = make_short4(l0, l1, l2, l3);
            }
            if (g + 2 * PBLK < NGRP) {
#pragma unroll
                for (int i = 0; i < 6; i++)
                    xr[i] = xbase[(size_t)(g + 2 * PBLK) * 3072 + t + i * 512];
            }
        }

        // ---- epilogue for group g ----
        // ssq per row. C/D (32x32): col=ln, rl=(r&3)+8*(r>>2)+4*hh.
        {
            float rs0[16], rs1[16];
#pragma unroll
            for (int r = 0; r < 16; r++) { rs0[r] = 0.f; rs1[r] = 0.f; }
#pragma unroll
            for (int j = 0; j < 5; j++) {
                const int mt = (j + ph) & 1;
                if (mt == 0) {
#pragma unroll
                    for (int r = 0; r < 16; r++) rs0[r] += acc[j][r] * acc[j][r];
                } else {
#pragma unroll
                    for (int r = 0; r < 16; r++) rs1[r] += acc[j][r] * acc[j][r];
                }
            }
#pragma unroll
            for (int r = 0; r < 16; r++) {
                float v0 = rs0[r], v1 = rs1[r];
                v0 += __shfl_xor(v0, 1);  v1 += __shfl_xor(v1, 1);
                v0 += __shfl_xor(v0, 2);  v1 += __shfl_xor(v1, 2);
                v0 += __shfl_xor(v0, 4);  v1 += __shfl_xor(v1, 4);
                v0 += __shfl_xor(v0, 8);  v1 += __shfl_xor(v1, 8);
                v0 += __shfl_xor(v0, 16); v1 += __shfl_xor(v1, 16);
                if (ln == 0) {
                    int rl = (r & 3) + ((r >> 2) << 3) + (hh << 2);
                    ssq_part[wv][rl] = v0;
                    ssq_part[wv][32 + rl] = v1;
                }
            }
        }
        __syncthreads();
        if (t < 64) {
            float s = 0.f;
#pragma unroll
            for (int w = 0; w < 8; w++) s += ssq_part[w][t];
            inv_s[t] = 1.f / fmaxf(sqrtf(s), 1e-12f);
        }
        __syncthreads();

        // hoist inv values (32 LDS broadcasts instead of 80)
        float iv0[16], iv1[16];
#pragma unroll
        for (int r = 0; r < 16; r++) {
            int rl = (r & 3) + ((r >> 2) << 3) + (hh << 2);
            iv0[r] = inv_s[rl];
            iv1[r] = inv_s[32 + rl];
        }
        // pooled[img][c] = sum_pos inv[row]*C[row][c]
#pragma unroll
        for (int j = 0; j < 5; j++) {
            const int mt  = (j + ph) & 1;
            const int nt  = ntBase + ((j + ph) >> 1);
            const int c   = nt * 32 + ln;
            float p0 = 0.f, p1 = 0.f;
#pragma unroll
            for (int r = 0; r < 16; r++) {
                float pv = acc[j][r] * ((mt == 0) ? iv0[r] : iv1[r]);
                if (r < 8) p0 += pv; else p1 += pv;
            }
            p0 += __shfl_xor(p0, 32);
            p1 += __shfl_xor(p1, 32);
            if (hh == 0) {
                pooled_s[(mt * 2 + 0) * CCH + c] = p0;
                pooled_s[(mt * 2 + 1) * CCH + c] = p1;
            }
        }
        __syncthreads();

        // per-image row L2-norm (2 waves per image)
        {
            int img = wv >> 1;
            int u = ((wv & 1) << 6) + l;
            float s = 0.f;
#pragma unroll
            for (int j = 0; j < 5; j++) {
                float pv = pooled_s[img * CCH + u + 128 * j];
                s += pv * pv;
            }
            s += __shfl_xor(s, 1);
            s += __shfl_xor(s, 2);
            s += __shfl_xor(s, 4);
            s += __shfl_xor(s, 8);
            s += __shfl_xor(s, 16);
            s += __shfl_xor(s, 32);
            if (l == 0) rn_part[wv] = s;
        }
        __syncthreads();
        if (t < 4)
            invc_s[t] = 1.f / fmaxf(sqrtf(rn_part[2 * t] + rn_part[2 * t + 1]), 1e-12f);
        __syncthreads();
#pragma unroll
        for (int e0 = 0; e0 < 5; e0++) {
            int e = t + e0 * 512;
            int im = e / CCH;
            int c2 = e - im * CCH;
            float v = pooled_s[e] * invc_s[im];
            short vh, vl;
            split_bf16(v, vh, vl);
            size_t o = ((size_t)g * 4 + im) * CCH + c2;
            fh[o] = vh;
            fl[o] = vl;
        }
        __syncthreads();   // protect pooled_s/A-LDS for next iteration
    }
}

// ---------------------------------------------------------------------------
// Kernel 2 v3: per (b,n). 45x9 sims via 16x16x32 MFMA (3-term bf16 split),
// then 5 parallel per-wave greedy solvers.
__global__ __launch_bounds__(320) void sim_mfma(
    const short* __restrict__ fh, const short* __restrict__ fl,
    float* __restrict__ out)                    // [8][75][5]
{
    __shared__ short qb_h[QKS * 64 * 8];        // 20.5 KB B-fragments (hi)
    __shared__ short qb_l[QKS * 64 * 8];        // 20.5 KB (lo)
    __shared__ float sims_s[WAY][84];

    const int n = blockIdx.x;
    const int b = blockIdx.y;
    const int t = threadIdx.x;

    // Stage Q B-fragments: lane l of frag ks holds Q_col(l&15)[ks*32+(l>>4)*8+j]
    for (int e = t; e < QKS * 64; e += 320) {
        int ks = e >> 6;
        int l2 = e & 63;
        int col = l2 & 15;
        int kb = ks * 32 + ((l2 >> 4) << 3);
        if (col < NP) {
            size_t qr = ((size_t)(b * NSAMP + WAY + n) * NP + col) * CCH + kb;
            *(bf16x8*)&qb_h[e * 8] = *(const bf16x8*)&fh[qr];
            *(bf16x8*)&qb_l[e * 8] = *(const bf16x8*)&fl[qr];
        } else {
            bf16x8 z = {0,0,0,0,0,0,0,0};
            *(bf16x8*)&qb_h[e * 8] = z;
            *(bf16x8*)&qb_l[e * 8] = z;
        }
    }
    __syncthreads();

    const int wv = t >> 6;
    const int l = t & 63;

    if (wv < 3) {
        // A rows: S-row idx = wv*16 + (l&15); m = idx*57>>9, h = idx-9m.
        int idx = wv * 16 + (l & 15);
        int m = (idx * 57) >> 9;
        int h = idx - 9 * m;
        int srow = (m < WAY) ? ((b * NSAMP + m) * NP + h) : (b * NSAMP * NP);
        const short* arh = fh + (size_t)srow * CCH + ((l >> 4) << 3);
        const short* arl = fl + (size_t)srow * CCH + ((l >> 4) << 3);
        f32x4 acc = {0.f, 0.f, 0.f, 0.f};
#pragma unroll
        for (int ks = 0; ks < QKS; ks++) {
            bf16x8 ah = *(const bf16x8*)&arh[ks * 32];
            bf16x8 al = *(const bf16x8*)&arl[ks * 32];
            bf16x8 bh = *(const bf16x8*)&qb_h[(ks * 64 + l) * 8];
            bf16x8 bl = *(const bf16x8*)&qb_l[(ks * 64 + l) * 8];
            acc = __builtin_amdgcn_mfma_f32_16x16x32_bf16(ah, bh, acc, 0, 0, 0);
            acc = __builtin_amdgcn_mfma_f32_16x16x32_bf16(al, bh, acc, 0, 0, 0);
            acc = __builtin_amdgcn_mfma_f32_16x16x32_bf16(ah, bl, acc, 0, 0, 0);
        }
        // C/D: col = l&15, row = (l>>4)*4 + r
        int col = l & 15;
#pragma unroll
        for (int r = 0; r < 4; r++) {
            int sidx = wv * 16 + (l >> 4) * 4 + r;
            if (sidx < 45 && col < NP) {
                int mm = (sidx * 57) >> 9;
                int hh2 = sidx - 9 * mm;
                sims_s[mm][hh2 * NP + col] = acc[r];
            }
        }
    }
    __syncthreads();

    // 5 waves, wave wv runs greedy for m = wv.
    {
        float v0 = sims_s[wv][l];
        float v1 = (l < 17) ? sims_s[wv][l + 64] : -3.0e38f;
        int d0r = l / NP, d0c = l - d0r * NP;
        int d1 = l + 64;
        int d1r = d1 / NP, d1c = d1 - d1r * NP;
        unsigned rm = 0x1FF, cm = 0x1FF;
        float total = 0.f, beta = 1.f;
        for (int it = 0; it < NP; it++) {
            float c0 = (((rm >> d0r) & 1u) && ((cm >> d0c) & 1u)) ? v0 : -3.0e38f;
            int i0 = l;
            float c1 = (l < 17 && ((rm >> d1r) & 1u) && ((cm >> d1c) & 1u)) ? v1 : -3.0e38f;
            if (c1 > c0) { c0 = c1; i0 = d1; }
#pragma unroll
            for (int off = 32; off >= 1; off >>= 1) {
                float ov = __shfl_xor(c0, off);
                int oi = __shfl_xor(i0, off);
                if (ov > c0 || (ov == c0 && oi < i0)) { c0 = ov; i0 = oi; }
            }
            total += fmaxf(c0, 0.f) * beta;
            beta *= 0.5f;
            int br = i0 / NP;
            int bc = i0 - br * NP;
            rm &= ~(1u << br);
            cm &= ~(1u << bc);
        }
        if (l == 0) out[((size_t)b * NQ + n) * WAY + wv] = total;
    }
}

extern "C" void kernel_launch(void* const* d_in, const int* in_sizes, int n_in,
                              void* d_out, int out_size, void* d_ws, size_t ws_size,
                              hipStream_t stream) {
    const float* data = (const float*)d_in[0];
    const float* conv_w = (const float*)d_in[1];

    short* fh   = (short*)d_ws;                      // 7,372,800 B
    short* fl   = fh + (size_t)NIMG * CCH;           // 7,372,800 B
    short* w_hi = fl + (size_t)NIMG * CCH;           // 245,760 B
    short* w_lo = w_hi + (size_t)NFRAG * 8;          // 245,760 B

    prep_w_pack<<<(CCH * KLEN / 4 + 255) / 256, 256, 0, stream>>>(conv_w, w_hi, w_lo);
    conv_mfma<<<PBLK, 512, 0, stream>>>(data, w_hi, w_lo, fh, fl);
    dim3 grid(NQ, BATCH);
    sim_mfma<<<grid, 320, 0, stream>>>(fh, fl, (float*)d_out);
}

// Round 8
// 223.036 us; speedup vs baseline: 1.4521x; 1.4521x over previous
//
#include <hip/hip_runtime.h>
#include <math.h>

// Problem constants
#define BATCH 8
#define WAY 5
#define NQ 75
#define NSAMP 80
#define NP 9
#define CCH 640
#define KLEN 192
#define NIMG (BATCH*NSAMP*NP)   // 5760
#define AS 200                  // LDS row stride (bf16 elems) for A tiles
#define NTILES 20               // 640/32 n-tiles
#define NKS 12                  // 192/16 k-steps
#define NFRAG (NTILES*NKS*64)   // 15360 lane-fragments per plane
#define QKS 20                  // 640/32 k-steps for sim MFMA

typedef short bf16x8 __attribute__((ext_vector_type(8)));
typedef float f32x16 __attribute__((ext_vector_type(16)));
typedef float f32x4  __attribute__((ext_vector_type(4)));

__device__ __forceinline__ void split_bf16(float x, short& hi, short& lo) {
    unsigned xb = __float_as_uint(x);
    hi = (short)(xb >> 16);
    float hf = __uint_as_float(xb & 0xFFFF0000u);
    float r = x - hf;
    lo = (short)(__float_as_uint(r) >> 16);
}

// ---------------------------------------------------------------------------
// Prep: split conv_w (640x192 fp32) into packed bf16 hi/lo B-fragments.
// Fragment f = nt*12+ks, lane l, elem j: w[nt*32+(l&31)][ks*16+(l>>5)*8+j].
__global__ __launch_bounds__(256) void prep_w_pack(
    const float* __restrict__ w, short* __restrict__ w_hi, short* __restrict__ w_lo)
{
    int f = blockIdx.x * 256 + threadIdx.x;   // float4 index, < 30720
    if (f < CCH * KLEN / 4) {
        int c  = f / 48;
        int kq = f - c * 48;                  // k = kq*4
        int nt = c >> 5;
        int ks = kq >> 2;
        int lane = (c & 31) | (((kq >> 1) & 1) << 5);
        int j = (kq & 1) << 2;
        float4 v = ((const float4*)w)[f];
        short h0, h1, h2, h3, l0, l1, l2, l3;
        split_bf16(v.x, h0, l0);
        split_bf16(v.y, h1, l1);
        split_bf16(v.z, h2, l2);
        split_bf16(v.w, h3, l3);
        size_t dst = ((size_t)(nt * NKS + ks) * 64 + lane) * 8 + j;
        *(short4*)(w_hi + dst) = make_short4(h0, h1, h2, h3);
        *(short4*)(w_lo + dst) = make_short4(l0, l1, l2, l3);
    }
}

// ---------------------------------------------------------------------------
// GEMM inner loop (phase-templated). Wave owns tiles tau = 5*wv + j:
// nt = tau>>1, Mt = tau&1. ks-outer: A read once per ks, reused over 3 nt.
// B prefetch ring DISTANCE 4: issue->consume gap ~480 MFMA-cycles, fully
// covering L2 latency. ~96 VGPRs of B in flight (budget 256/wave at 2 w/EU).
template<int PH>
__device__ __forceinline__ void gemm_loop(
    const short* __restrict__ Ah, const short* __restrict__ Al,
    const bf16x8* __restrict__ BH, const bf16x8* __restrict__ BL,
    int abase, f32x16 acc[5])
{
    bf16x8 rh[4][3], rl[4][3];
#pragma unroll
    for (int s = 0; s < 4; s++)
#pragma unroll
        for (int r = 0; r < 3; r++) {
            rh[s][r] = BH[(r * NKS + s) * 64];
            rl[s][r] = BL[(r * NKS + s) * 64];
        }
#pragma unroll
    for (int ks = 0; ks < NKS; ks++) {
        const int s = ks & 3;
        bf16x8 aH0 = *(const bf16x8*)&Ah[abase + ks * 16];
        bf16x8 aL0 = *(const bf16x8*)&Al[abase + ks * 16];
        bf16x8 aH1 = *(const bf16x8*)&Ah[abase + 32 * AS + ks * 16];
        bf16x8 aL1 = *(const bf16x8*)&Al[abase + 32 * AS + ks * 16];
#pragma unroll
        for (int j = 0; j < 5; j++) {
            const int mt  = (j + PH) & 1;
            const int rel = (j + PH) >> 1;
            bf16x8 ah = (mt == 0) ? aH0 : aH1;
            bf16x8 al = (mt == 0) ? aL0 : aL1;
            acc[j] = __builtin_amdgcn_mfma_f32_32x32x16_bf16(ah, rh[s][rel], acc[j], 0, 0, 0);
            acc[j] = __builtin_amdgcn_mfma_f32_32x32x16_bf16(al, rh[s][rel], acc[j], 0, 0, 0);
            acc[j] = __builtin_amdgcn_mfma_f32_32x32x16_bf16(ah, rl[s][rel], acc[j], 0, 0, 0);
        }
        if (ks + 4 < NKS) {
#pragma unroll
            for (int r = 0; r < 3; r++) {
                rh[s][r] = BH[(r * NKS + ks + 4) * 64];
                rl[s][r] = BL[(r * NKS + ks + 4) * 64];
            }
        }
    }
}

// ---------------------------------------------------------------------------
// Kernel 1: per block = 4 patch-images (M=64 = 2 M-tiles). 8 waves x 5 tiles
// (exactly balanced, 80 acc AGPRs/wave). bf16 hi/lo 3-term split GEMM +
// per-position L2 norm + mean-pool + per-image L2 norm.
// Output: featn as bf16 hi/lo planes (consumed by sim_mfma).
__global__ __launch_bounds__(512, 2) void conv_mfma(
    const float* __restrict__ x,      // [NIMG,3,32,32]
    const short* __restrict__ w_hi,   // packed B-fragments
    const short* __restrict__ w_lo,
    short* __restrict__ fh,           // [NIMG][640] bf16 hi
    short* __restrict__ fl)           // [NIMG][640] bf16 lo
{
    __shared__ short Ah[64 * AS];             // 25.6 KB
    __shared__ short Al[64 * AS];             // 25.6 KB
    __shared__ float ssq_part[8][64];
    __shared__ float inv_s[64];
    __shared__ float pooled_s[4 * CCH];       // 10.2 KB
    __shared__ float rn_part[8];
    __shared__ float invc_s[4];

    const int t = threadIdx.x;
    const int blk = blockIdx.x;

    // ---- load 4 images, rearrange to A[row=img*16+pos][k], split hi/lo
    {
        const float4* xp = (const float4*)(x + (size_t)blk * 4 * 3072);
#pragma unroll
        for (int i = 0; i < 6; i++) {
            int f = t + i * 512;              // 0..3071 float4s
            int img = f / 768;
            int rem = f - img * 768;
            int ci = rem >> 8;
            int rem2 = rem & 255;
            int h = rem2 >> 3;
            int w4 = (rem2 & 7) << 2;
            int s = ((h >> 3) << 2) + (w4 >> 3);
            int k0 = (ci << 6) + ((h & 7) << 3) + (w4 & 7);
            int row = (img << 4) + s;
            float4 v = xp[f];
            short h0, h1, h2, h3, l0, l1, l2, l3;
            split_bf16(v.x, h0, l0);
            split_bf16(v.y, h1, l1);
            split_bf16(v.z, h2, l2);
            split_bf16(v.w, h3, l3);
            *(short4*)&Ah[row * AS + k0] = make_short4(h0, h1, h2, h3);
            *(short4*)&Al[row * AS + k0] = make_short4(l0, l1, l2, l3);
        }
    }
    __syncthreads();

    const int wv = t >> 6;       // wave 0..7
    const int l  = t & 63;
    const int ln = l & 31;       // MFMA col lane
    const int hh = l >> 5;       // k-half
    const int ph = wv & 1;       // phase: tau0 = 5*wv, ph = tau0 & 1
    const int ntBase = (5 * wv) >> 1;

    f32x16 acc[5];
#pragma unroll
    for (int j = 0; j < 5; j++)
#pragma unroll
        for (int r = 0; r < 16; r++) acc[j][r] = 0.f;

    const bf16x8* BH = (const bf16x8*)w_hi + (size_t)ntBase * (NKS * 64) + l;
    const bf16x8* BL = (const bf16x8*)w_lo + (size_t)ntBase * (NKS * 64) + l;
    const int abase = ln * AS + hh * 8;

    if (ph == 0) gemm_loop<0>(Ah, Al, BH, BL, abase, acc);
    else         gemm_loop<1>(Ah, Al, BH, BL, abase, acc);

    // ---- ssq per row. C/D layout (32x32): col=ln, rl=(r&3)+8*(r>>2)+4*hh.
    {
        float rs0[16], rs1[16];
#pragma unroll
        for (int r = 0; r < 16; r++) { rs0[r] = 0.f; rs1[r] = 0.f; }
#pragma unroll
        for (int j = 0; j < 5; j++) {
            const int mt = (j + ph) & 1;      // wave-uniform
            if (mt == 0) {
#pragma unroll
                for (int r = 0; r < 16; r++) rs0[r] += acc[j][r] * acc[j][r];
            } else {
#pragma unroll
                for (int r = 0; r < 16; r++) rs1[r] += acc[j][r] * acc[j][r];
            }
        }
#pragma unroll
        for (int r = 0; r < 16; r++) {
            float v0 = rs0[r], v1 = rs1[r];
            v0 += __shfl_xor(v0, 1);  v1 += __shfl_xor(v1, 1);
            v0 += __shfl_xor(v0, 2);  v1 += __shfl_xor(v1, 2);
            v0 += __shfl_xor(v0, 4);  v1 += __shfl_xor(v1, 4);
            v0 += __shfl_xor(v0, 8);  v1 += __shfl_xor(v1, 8);
            v0 += __shfl_xor(v0, 16); v1 += __shfl_xor(v1, 16);
            if (ln == 0) {
                int rl = (r & 3) + ((r >> 2) << 3) + (hh << 2);
                ssq_part[wv][rl] = v0;
                ssq_part[wv][32 + rl] = v1;
            }
        }
    }
    __syncthreads();
    if (t < 64) {
        float s = 0.f;
#pragma unroll
        for (int w = 0; w < 8; w++) s += ssq_part[w][t];
        inv_s[t] = 1.f / fmaxf(sqrtf(s), 1e-12f);
    }
    __syncthreads();

    // hoisted inv broadcasts (32 LDS reads instead of 80)
    float iv0[16], iv1[16];
#pragma unroll
    for (int r = 0; r < 16; r++) {
        int rl = (r & 3) + ((r >> 2) << 3) + (hh << 2);
        iv0[r] = inv_s[rl];
        iv1[r] = inv_s[32 + rl];
    }

    // ---- pooled[img][c] = sum_pos inv[row]*C[row][c]; img = mt*2 + (r>=8)
#pragma unroll
    for (int j = 0; j < 5; j++) {
        const int mt  = (j + ph) & 1;
        const int nt  = ntBase + ((j + ph) >> 1);
        const int c   = nt * 32 + ln;
        float p0 = 0.f, p1 = 0.f;
#pragma unroll
        for (int r = 0; r < 16; r++) {
            float pv = acc[j][r] * ((mt == 0) ? iv0[r] : iv1[r]);
            if (r < 8) p0 += pv; else p1 += pv;
        }
        p0 += __shfl_xor(p0, 32);
        p1 += __shfl_xor(p1, 32);
        if (hh == 0) {
            pooled_s[(mt * 2 + 0) * CCH + c] = p0;
            pooled_s[(mt * 2 + 1) * CCH + c] = p1;
        }
    }
    __syncthreads();

    // ---- per-image row L2-norm (2 waves per image)
    {
        int img = wv >> 1;
        int u = ((wv & 1) << 6) + l;
        float s = 0.f;
#pragma unroll
        for (int j = 0; j < 5; j++) {
            float pv = pooled_s[img * CCH + u + 128 * j];
            s += pv * pv;
        }
        s += __shfl_xor(s, 1);
        s += __shfl_xor(s, 2);
        s += __shfl_xor(s, 4);
        s += __shfl_xor(s, 8);
        s += __shfl_xor(s, 16);
        s += __shfl_xor(s, 32);
        if (l == 0) rn_part[wv] = s;
    }
    __syncthreads();
    if (t < 4)
        invc_s[t] = 1.f / fmaxf(sqrtf(rn_part[2 * t] + rn_part[2 * t + 1]), 1e-12f);
    __syncthreads();
#pragma unroll
    for (int e0 = 0; e0 < 5; e0++) {
        int e = t + e0 * 512;
        int im = e / CCH;
        int c2 = e - im * CCH;
        float v = pooled_s[e] * invc_s[im];
        short vh, vl;
        split_bf16(v, vh, vl);
        size_t o = ((size_t)blk * 4 + im) * CCH + c2;
        fh[o] = vh;
        fl[o] = vl;
    }
}

// ---------------------------------------------------------------------------
// Kernel 2: per (b,n). 45x9 sims via 16x16x32 MFMA (3-term bf16 split),
// then 5 parallel per-wave greedy solvers.
__global__ __launch_bounds__(320) void sim_mfma(
    const short* __restrict__ fh, const short* __restrict__ fl,
    float* __restrict__ out)                    // [8][75][5]
{
    __shared__ short qb_h[QKS * 64 * 8];        // 20.5 KB B-fragments (hi)
    __shared__ short qb_l[QKS * 64 * 8];        // 20.5 KB (lo)
    __shared__ float sims_s[WAY][84];

    const int n = blockIdx.x;
    const int b = blockIdx.y;
    const int t = threadIdx.x;

    // Stage Q B-fragments: lane l of frag ks holds Q_col(l&15)[ks*32+(l>>4)*8+j]
    for (int e = t; e < QKS * 64; e += 320) {
        int ks = e >> 6;
        int l2 = e & 63;
        int col = l2 & 15;
        int kb = ks * 32 + ((l2 >> 4) << 3);
        if (col < NP) {
            size_t qr = ((size_t)(b * NSAMP + WAY + n) * NP + col) * CCH + kb;
            *(bf16x8*)&qb_h[e * 8] = *(const bf16x8*)&fh[qr];
            *(bf16x8*)&qb_l[e * 8] = *(const bf16x8*)&fl[qr];
        } else {
            bf16x8 z = {0,0,0,0,0,0,0,0};
            *(bf16x8*)&qb_h[e * 8] = z;
            *(bf16x8*)&qb_l[e * 8] = z;
        }
    }
    __syncthreads();

    const int wv = t >> 6;
    const int l = t & 63;

    if (wv < 3) {
        // A rows: S-row idx = wv*16 + (l&15); m = idx*57>>9, h = idx-9m.
        int idx = wv * 16 + (l & 15);
        int m = (idx * 57) >> 9;
        int h = idx - 9 * m;
        int srow = (m < WAY) ? ((b * NSAMP + m) * NP + h) : (b * NSAMP * NP);
        const short* arh = fh + (size_t)srow * CCH + ((l >> 4) << 3);
        const short* arl = fl + (size_t)srow * CCH + ((l >> 4) << 3);
        f32x4 acc = {0.f, 0.f, 0.f, 0.f};
#pragma unroll
        for (int ks = 0; ks < QKS; ks++) {
            bf16x8 ah = *(const bf16x8*)&arh[ks * 32];
            bf16x8 al = *(const bf16x8*)&arl[ks * 32];
            bf16x8 bh = *(const bf16x8*)&qb_h[(ks * 64 + l) * 8];
            bf16x8 bl = *(const bf16x8*)&qb_l[(ks * 64 + l) * 8];
            acc = __builtin_amdgcn_mfma_f32_16x16x32_bf16(ah, bh, acc, 0, 0, 0);
            acc = __builtin_amdgcn_mfma_f32_16x16x32_bf16(al, bh, acc, 0, 0, 0);
            acc = __builtin_amdgcn_mfma_f32_16x16x32_bf16(ah, bl, acc, 0, 0, 0);
        }
        // C/D: col = l&15, row = (l>>4)*4 + r
        int col = l & 15;
#pragma unroll
        for (int r = 0; r < 4; r++) {
            int sidx = wv * 16 + (l >> 4) * 4 + r;
            if (sidx < 45 && col < NP) {
                int mm = (sidx * 57) >> 9;
                int hh2 = sidx - 9 * mm;
                sims_s[mm][hh2 * NP + col] = acc[r];
            }
        }
    }
    __syncthreads();

    // 5 waves, wave wv runs greedy for m = wv.
    {
        float v0 = sims_s[wv][l];
        float v1 = (l < 17) ? sims_s[wv][l + 64] : -3.0e38f;
        int d0r = l / NP, d0c = l - d0r * NP;
        int d1 = l + 64;
        int d1r = d1 / NP, d1c = d1 - d1r * NP;
        unsigned rm = 0x1FF, cm = 0x1FF;
        float total = 0.f, beta = 1.f;
        for (int it = 0; it < NP; it++) {
            float c0 = (((rm >> d0r) & 1u) && ((cm >> d0c) & 1u)) ? v0 : -3.0e38f;
            int i0 = l;
            float c1 = (l < 17 && ((rm >> d1r) & 1u) && ((cm >> d1c) & 1u)) ? v1 : -3.0e38f;
            if (c1 > c0) { c0 = c1; i0 = d1; }
#pragma unroll
            for (int off = 32; off >= 1; off >>= 1) {
                float ov = __shfl_xor(c0, off);
                int oi = __shfl_xor(i0, off);
                if (ov > c0 || (ov == c0 && oi < i0)) { c0 = ov; i0 = oi; }
            }
            total += fmaxf(c0, 0.f) * beta;
            beta *= 0.5f;
            int br = i0 / NP;
            int bc = i0 - br * NP;
            rm &= ~(1u << br);
            cm &= ~(1u << bc);
        }
        if (l == 0) out[((size_t)b * NQ + n) * WAY + wv] = total;
    }
}

extern "C" void kernel_launch(void* const* d_in, const int* in_sizes, int n_in,
                              void* d_out, int out_size, void* d_ws, size_t ws_size,
                              hipStream_t stream) {
    const float* data = (const float*)d_in[0];
    const float* conv_w = (const float*)d_in[1];

    short* fh   = (short*)d_ws;                      // 7,372,800 B
    short* fl   = fh + (size_t)NIMG * CCH;           // 7,372,800 B
    short* w_hi = fl + (size_t)NIMG * CCH;           // 245,760 B
    short* w_lo = w_hi + (size_t)NFRAG * 8;          // 245,760 B

    prep_w_pack<<<(CCH * KLEN / 4 + 255) / 256, 256, 0, stream>>>(conv_w, w_hi, w_lo);
    conv_mfma<<<NIMG / 4, 512, 0, stream>>>(data, w_hi, w_lo, fh, fl);
    dim3 grid(NQ, BATCH);
    sim_mfma<<<grid, 320, 0, stream>>>(fh, fl, (float*)d_out);
}

// Round 9
// 200.124 us; speedup vs baseline: 1.6183x; 1.1145x over previous
//
#include <hip/hip_runtime.h>
#include <math.h>

// Problem constants
#define BATCH 8
#define WAY 5
#define NQ 75
#define NSAMP 80
#define NP 9
#define CCH 640
#define KLEN 192
#define NIMG (BATCH*NSAMP*NP)   // 5760
#define AS 200                  // LDS row stride (bf16 elems) for A tiles
#define NTILES 20               // 640/32 n-tiles
#define NKS 12                  // 192/16 k-steps
#define NFRAG (NTILES*NKS*64)   // 15360 lane-fragments per plane
#define QKS 20                  // 640/32 k-steps for sim MFMA

typedef short bf16x8 __attribute__((ext_vector_type(8)));
typedef float f32x16 __attribute__((ext_vector_type(16)));
typedef float f32x4  __attribute__((ext_vector_type(4)));

__device__ __forceinline__ void split_bf16(float x, short& hi, short& lo) {
    unsigned xb = __float_as_uint(x);
    hi = (short)(xb >> 16);
    float hf = __uint_as_float(xb & 0xFFFF0000u);
    float r = x - hf;
    lo = (short)(__float_as_uint(r) >> 16);
}

// ---------------------------------------------------------------------------
// Prep: split conv_w (640x192 fp32) into packed bf16 hi/lo B-fragments.
// Fragment f = nt*12+ks, lane l, elem j: w[nt*32+(l&31)][ks*16+(l>>5)*8+j].
__global__ __launch_bounds__(256) void prep_w_pack(
    const float* __restrict__ w, short* __restrict__ w_hi, short* __restrict__ w_lo)
{
    int f = blockIdx.x * 256 + threadIdx.x;   // float4 index, < 30720
    if (f < CCH * KLEN / 4) {
        int c  = f / 48;
        int kq = f - c * 48;                  // k = kq*4
        int nt = c >> 5;
        int ks = kq >> 2;
        int lane = (c & 31) | (((kq >> 1) & 1) << 5);
        int j = (kq & 1) << 2;
        float4 v = ((const float4*)w)[f];
        short h0, h1, h2, h3, l0, l1, l2, l3;
        split_bf16(v.x, h0, l0);
        split_bf16(v.y, h1, l1);
        split_bf16(v.z, h2, l2);
        split_bf16(v.w, h3, l3);
        size_t dst = ((size_t)(nt * NKS + ks) * 64 + lane) * 8 + j;
        *(short4*)(w_hi + dst) = make_short4(h0, h1, h2, h3);
        *(short4*)(w_lo + dst) = make_short4(l0, l1, l2, l3);
    }
}

// ---------------------------------------------------------------------------
// Kernel 1 v4: 256-thread blocks (4 waves), M=64 (4 images), 2 blocks/CU.
// Wave w owns nt = 5w..5w+4, BOTH M-tiles: acc[i*2+mt], 160 AGPR/wave.
// Per-nt B loads with a distance-1 register ring (32 VGPR in flight) keep
// arch VGPRs ~<96 so 2 waves/SIMD (one per block) co-reside: one block's
// K-loop hides the other's staging/epilogue.
__global__ __launch_bounds__(256, 2) void conv_mfma(
    const float* __restrict__ x,      // [NIMG,3,32,32]
    const short* __restrict__ w_hi,   // packed B-fragments
    const short* __restrict__ w_lo,
    short* __restrict__ fh,           // [NIMG][640] bf16 hi
    short* __restrict__ fl)           // [NIMG][640] bf16 lo
{
    __shared__ short Ah[64 * AS];             // 25.6 KB
    __shared__ short Al[64 * AS];             // 25.6 KB
    __shared__ float ssq_part[4][64];         // 1 KB
    __shared__ float inv_s[64];
    __shared__ float pooled_s[4 * CCH];       // 10.2 KB
    __shared__ float rn_part[4];
    __shared__ float invc_s[4];

    const int t = threadIdx.x;
    const int blk = blockIdx.x;

    // ---- load 4 images, rearrange to A[row=img*16+pos][k], split hi/lo
    {
        const float4* xp = (const float4*)(x + (size_t)blk * 4 * 3072);
#pragma unroll
        for (int i = 0; i < 12; i++) {
            int f = t + i * 256;              // 0..3071 float4s
            int img = f / 768;
            int rem = f - img * 768;
            int ci = rem >> 8;
            int rem2 = rem & 255;
            int h = rem2 >> 3;
            int w4 = (rem2 & 7) << 2;
            int s = ((h >> 3) << 2) + (w4 >> 3);
            int k0 = (ci << 6) + ((h & 7) << 3) + (w4 & 7);
            int row = (img << 4) + s;
            float4 v = xp[f];
            short h0, h1, h2, h3, l0, l1, l2, l3;
            split_bf16(v.x, h0, l0);
            split_bf16(v.y, h1, l1);
            split_bf16(v.z, h2, l2);
            split_bf16(v.w, h3, l3);
            *(short4*)&Ah[row * AS + k0] = make_short4(h0, h1, h2, h3);
            *(short4*)&Al[row * AS + k0] = make_short4(l0, l1, l2, l3);
        }
    }
    __syncthreads();

    const int wv = t >> 6;       // wave 0..3
    const int l  = t & 63;
    const int ln = l & 31;       // MFMA col lane
    const int hh = l >> 5;       // k-half

    f32x16 acc[10];              // acc[i*2 + mt]
#pragma unroll
    for (int j = 0; j < 10; j++)
#pragma unroll
        for (int r = 0; r < 16; r++) acc[j][r] = 0.f;

    const bf16x8* BH = (const bf16x8*)w_hi + (size_t)(wv * 5) * (NKS * 64) + l;
    const bf16x8* BL = (const bf16x8*)w_lo + (size_t)(wv * 5) * (NKS * 64) + l;
    const int abase = ln * AS + hh * 8;

    // K-loop: flat p = ks*5 + i (ks-outer so A is read once per ks).
    // B offset for (i,ks): (i*NKS + ks)*64. Distance-1 register ring.
    {
        bf16x8 cbh = BH[0], cbl = BL[0];      // (ks=0, i=0)
        bf16x8 aH0, aL0, aH1, aL1;
#pragma unroll
        for (int p = 0; p < 60; p++) {
            const int ks = p / 5;
            const int i  = p % 5;
            bf16x8 bh = cbh, bl = cbl;
            if (p + 1 < 60) {
                const int pn = p + 1;
                const int off = ((pn % 5) * NKS + pn / 5) * 64;
                cbh = BH[off];
                cbl = BL[off];
            }
            if (i == 0) {
                aH0 = *(const bf16x8*)&Ah[abase + ks * 16];
                aL0 = *(const bf16x8*)&Al[abase + ks * 16];
                aH1 = *(const bf16x8*)&Ah[abase + 32 * AS + ks * 16];
                aL1 = *(const bf16x8*)&Al[abase + 32 * AS + ks * 16];
            }
            acc[i * 2 + 0] = __builtin_amdgcn_mfma_f32_32x32x16_bf16(aH0, bh, acc[i * 2 + 0], 0, 0, 0);
            acc[i * 2 + 0] = __builtin_amdgcn_mfma_f32_32x32x16_bf16(aL0, bh, acc[i * 2 + 0], 0, 0, 0);
            acc[i * 2 + 0] = __builtin_amdgcn_mfma_f32_32x32x16_bf16(aH0, bl, acc[i * 2 + 0], 0, 0, 0);
            acc[i * 2 + 1] = __builtin_amdgcn_mfma_f32_32x32x16_bf16(aH1, bh, acc[i * 2 + 1], 0, 0, 0);
            acc[i * 2 + 1] = __builtin_amdgcn_mfma_f32_32x32x16_bf16(aL1, bh, acc[i * 2 + 1], 0, 0, 0);
            acc[i * 2 + 1] = __builtin_amdgcn_mfma_f32_32x32x16_bf16(aH1, bl, acc[i * 2 + 1], 0, 0, 0);
        }
    }

    // ---- ssq per row. C/D layout (32x32): col=ln, rl=(r&3)+8*(r>>2)+4*hh.
    {
        float rs0[16], rs1[16];
#pragma unroll
        for (int r = 0; r < 16; r++) { rs0[r] = 0.f; rs1[r] = 0.f; }
#pragma unroll
        for (int i = 0; i < 5; i++) {
#pragma unroll
            for (int r = 0; r < 16; r++) {
                rs0[r] += acc[i * 2 + 0][r] * acc[i * 2 + 0][r];
                rs1[r] += acc[i * 2 + 1][r] * acc[i * 2 + 1][r];
            }
        }
#pragma unroll
        for (int r = 0; r < 16; r++) {
            float v0 = rs0[r], v1 = rs1[r];
            v0 += __shfl_xor(v0, 1);  v1 += __shfl_xor(v1, 1);
            v0 += __shfl_xor(v0, 2);  v1 += __shfl_xor(v1, 2);
            v0 += __shfl_xor(v0, 4);  v1 += __shfl_xor(v1, 4);
            v0 += __shfl_xor(v0, 8);  v1 += __shfl_xor(v1, 8);
            v0 += __shfl_xor(v0, 16); v1 += __shfl_xor(v1, 16);
            if (ln == 0) {
                int rl = (r & 3) + ((r >> 2) << 3) + (hh << 2);
                ssq_part[wv][rl] = v0;
                ssq_part[wv][32 + rl] = v1;
            }
        }
    }
    __syncthreads();
    if (t < 64) {
        float s = ssq_part[0][t] + ssq_part[1][t] + ssq_part[2][t] + ssq_part[3][t];
        inv_s[t] = 1.f / fmaxf(sqrtf(s), 1e-12f);
    }
    __syncthreads();

    // hoisted inv broadcasts (32 LDS reads / thread)
    float iv0[16], iv1[16];
#pragma unroll
    for (int r = 0; r < 16; r++) {
        int rl = (r & 3) + ((r >> 2) << 3) + (hh << 2);
        iv0[r] = inv_s[rl];
        iv1[r] = inv_s[32 + rl];
    }

    // ---- pooled[img][c] = sum_pos inv[row]*C[row][c]; img = mt*2 + (r>=8)
#pragma unroll
    for (int i = 0; i < 5; i++) {
        const int c = (wv * 5 + i) * 32 + ln;
#pragma unroll
        for (int mt = 0; mt < 2; mt++) {
            float p0 = 0.f, p1 = 0.f;
#pragma unroll
            for (int r = 0; r < 16; r++) {
                float pv = acc[i * 2 + mt][r] * ((mt == 0) ? iv0[r] : iv1[r]);
                if (r < 8) p0 += pv; else p1 += pv;
            }
            p0 += __shfl_xor(p0, 32);
            p1 += __shfl_xor(p1, 32);
            if (hh == 0) {
                pooled_s[(mt * 2 + 0) * CCH + c] = p0;
                pooled_s[(mt * 2 + 1) * CCH + c] = p1;
            }
        }
    }
    __syncthreads();

    // ---- per-image row L2-norm (wave wv handles image wv)
    {
        float s = 0.f;
#pragma unroll
        for (int j = 0; j < 10; j++) {
            float pv = pooled_s[wv * CCH + l + 64 * j];
            s += pv * pv;
        }
        s += __shfl_xor(s, 1);
        s += __shfl_xor(s, 2);
        s += __shfl_xor(s, 4);
        s += __shfl_xor(s, 8);
        s += __shfl_xor(s, 16);
        s += __shfl_xor(s, 32);
        if (l == 0) rn_part[wv] = s;
    }
    __syncthreads();
    if (t < 4)
        invc_s[t] = 1.f / fmaxf(sqrtf(rn_part[t]), 1e-12f);
    __syncthreads();
#pragma unroll
    for (int e0 = 0; e0 < 10; e0++) {
        int e = t + e0 * 256;                 // 0..2559
        int im = e / CCH;
        int c2 = e - im * CCH;
        float v = pooled_s[e] * invc_s[im];
        short vh, vl;
        split_bf16(v, vh, vl);
        size_t o = ((size_t)blk * 4 + im) * CCH + c2;
        fh[o] = vh;
        fl[o] = vl;
    }
}

// ---------------------------------------------------------------------------
// Kernel 2: per (b,n). 45x9 sims via 16x16x32 MFMA (3-term bf16 split),
// then 5 parallel per-wave greedy solvers.
__global__ __launch_bounds__(320) void sim_mfma(
    const short* __restrict__ fh, const short* __restrict__ fl,
    float* __restrict__ out)                    // [8][75][5]
{
    __shared__ short qb_h[QKS * 64 * 8];        // 20.5 KB B-fragments (hi)
    __shared__ short qb_l[QKS * 64 * 8];        // 20.5 KB (lo)
    __shared__ float sims_s[WAY][84];

    const int n = blockIdx.x;
    const int b = blockIdx.y;
    const int t = threadIdx.x;

    // Stage Q B-fragments: lane l of frag ks holds Q_col(l&15)[ks*32+(l>>4)*8+j]
    for (int e = t; e < QKS * 64; e += 320) {
        int ks = e >> 6;
        int l2 = e & 63;
        int col = l2 & 15;
        int kb = ks * 32 + ((l2 >> 4) << 3);
        if (col < NP) {
            size_t qr = ((size_t)(b * NSAMP + WAY + n) * NP + col) * CCH + kb;
            *(bf16x8*)&qb_h[e * 8] = *(const bf16x8*)&fh[qr];
            *(bf16x8*)&qb_l[e * 8] = *(const bf16x8*)&fl[qr];
        } else {
            bf16x8 z = {0,0,0,0,0,0,0,0};
            *(bf16x8*)&qb_h[e * 8] = z;
            *(bf16x8*)&qb_l[e * 8] = z;
        }
    }
    __syncthreads();

    const int wv = t >> 6;
    const int l = t & 63;

    if (wv < 3) {
        // A rows: S-row idx = wv*16 + (l&15); m = idx*57>>9, h = idx-9m.
        int idx = wv * 16 + (l & 15);
        int m = (idx * 57) >> 9;
        int h = idx - 9 * m;
        int srow = (m < WAY) ? ((b * NSAMP + m) * NP + h) : (b * NSAMP * NP);
        const short* arh = fh + (size_t)srow * CCH + ((l >> 4) << 3);
        const short* arl = fl + (size_t)srow * CCH + ((l >> 4) << 3);
        f32x4 acc = {0.f, 0.f, 0.f, 0.f};
#pragma unroll
        for (int ks = 0; ks < QKS; ks++) {
            bf16x8 ah = *(const bf16x8*)&arh[ks * 32];
            bf16x8 al = *(const bf16x8*)&arl[ks * 32];
            bf16x8 bh = *(const bf16x8*)&qb_h[(ks * 64 + l) * 8];
            bf16x8 bl = *(const bf16x8*)&qb_l[(ks * 64 + l) * 8];
            acc = __builtin_amdgcn_mfma_f32_16x16x32_bf16(ah, bh, acc, 0, 0, 0);
            acc = __builtin_amdgcn_mfma_f32_16x16x32_bf16(al, bh, acc, 0, 0, 0);
            acc = __builtin_amdgcn_mfma_f32_16x16x32_bf16(ah, bl, acc, 0, 0, 0);
        }
        // C/D: col = l&15, row = (l>>4)*4 + r
        int col = l & 15;
#pragma unroll
        for (int r = 0; r < 4; r++) {
            int sidx = wv * 16 + (l >> 4) * 4 + r;
            if (sidx < 45 && col < NP) {
                int mm = (sidx * 57) >> 9;
                int hh2 = sidx - 9 * mm;
                sims_s[mm][hh2 * NP + col] = acc[r];
            }
        }
    }
    __syncthreads();

    // 5 waves, wave wv runs greedy for m = wv.
    {
        float v0 = sims_s[wv][l];
        float v1 = (l < 17) ? sims_s[wv][l + 64] : -3.0e38f;
        int d0r = l / NP, d0c = l - d0r * NP;
        int d1 = l + 64;
        int d1r = d1 / NP, d1c = d1 - d1r * NP;
        unsigned rm = 0x1FF, cm = 0x1FF;
        float total = 0.f, beta = 1.f;
        for (int it = 0; it < NP; it++) {
            float c0 = (((rm >> d0r) & 1u) && ((cm >> d0c) & 1u)) ? v0 : -3.0e38f;
            int i0 = l;
            float c1 = (l < 17 && ((rm >> d1r) & 1u) && ((cm >> d1c) & 1u)) ? v1 : -3.0e38f;
            if (c1 > c0) { c0 = c1; i0 = d1; }
#pragma unroll
            for (int off = 32; off >= 1; off >>= 1) {
                float ov = __shfl_xor(c0, off);
                int oi = __shfl_xor(i0, off);
                if (ov > c0 || (ov == c0 && oi < i0)) { c0 = ov; i0 = oi; }
            }
            total += fmaxf(c0, 0.f) * beta;
            beta *= 0.5f;
            int br = i0 / NP;
            int bc = i0 - br * NP;
            rm &= ~(1u << br);
            cm &= ~(1u << bc);
        }
        if (l == 0) out[((size_t)b * NQ + n) * WAY + wv] = total;
    }
}

extern "C" void kernel_launch(void* const* d_in, const int* in_sizes, int n_in,
                              void* d_out, int out_size, void* d_ws, size_t ws_size,
                              hipStream_t stream) {
    const float* data = (const float*)d_in[0];
    const float* conv_w = (const float*)d_in[1];

    short* fh   = (short*)d_ws;                      // 7,372,800 B
    short* fl   = fh + (size_t)NIMG * CCH;           // 7,372,800 B
    short* w_hi = fl + (size_t)NIMG * CCH;           // 245,760 B
    short* w_lo = w_hi + (size_t)NFRAG * 8;          // 245,760 B

    prep_w_pack<<<(CCH * KLEN / 4 + 255) / 256, 256, 0, stream>>>(conv_w, w_hi, w_lo);
    conv_mfma<<<NIMG / 4, 256, 0, stream>>>(data, w_hi, w_lo, fh, fl);
    dim3 grid(NQ, BATCH);
    sim_mfma<<<grid, 320, 0, stream>>>(fh, fl, (float*)d_out);
}

// Round 10
// 197.729 us; speedup vs baseline: 1.6379x; 1.0121x over previous
//
#include <hip/hip_runtime.h>
#include <math.h>

// Problem constants
#define BATCH 8
#define WAY 5
#define NQ 75
#define NSAMP 80
#define NP 9
#define CCH 640
#define KLEN 192
#define NIMG (BATCH*NSAMP*NP)   // 5760
#define AS 200                  // LDS row stride (bf16 elems) for A tiles
#define NTILES 20               // 640/32 n-tiles
#define NKS 12                  // 192/16 k-steps
#define NFRAG (NTILES*NKS*64)   // 15360 lane-fragments per plane
#define QKS 20                  // 640/32 k-steps for sim MFMA
#define NSET 3                  // 48 support rows = 3 sets of 16

typedef short bf16x8 __attribute__((ext_vector_type(8)));
typedef float f32x16 __attribute__((ext_vector_type(16)));
typedef float f32x4  __attribute__((ext_vector_type(4)));

__device__ __forceinline__ void split_bf16(float x, short& hi, short& lo) {
    unsigned xb = __float_as_uint(x);
    hi = (short)(xb >> 16);
    float hf = __uint_as_float(xb & 0xFFFF0000u);
    float r = x - hf;
    lo = (short)(__float_as_uint(r) >> 16);
}

// ---------------------------------------------------------------------------
// Prep: split conv_w (640x192 fp32) into packed bf16 hi/lo B-fragments.
// Fragment f = nt*12+ks, lane l, elem j: w[nt*32+(l&31)][ks*16+(l>>5)*8+j].
__global__ __launch_bounds__(256) void prep_w_pack(
    const float* __restrict__ w, short* __restrict__ w_hi, short* __restrict__ w_lo)
{
    int f = blockIdx.x * 256 + threadIdx.x;   // float4 index, < 30720
    if (f < CCH * KLEN / 4) {
        int c  = f / 48;
        int kq = f - c * 48;                  // k = kq*4
        int nt = c >> 5;
        int ks = kq >> 2;
        int lane = (c & 31) | (((kq >> 1) & 1) << 5);
        int j = (kq & 1) << 2;
        float4 v = ((const float4*)w)[f];
        short h0, h1, h2, h3, l0, l1, l2, l3;
        split_bf16(v.x, h0, l0);
        split_bf16(v.y, h1, l1);
        split_bf16(v.z, h2, l2);
        split_bf16(v.w, h3, l3);
        size_t dst = ((size_t)(nt * NKS + ks) * 64 + lane) * 8 + j;
        *(short4*)(w_hi + dst) = make_short4(h0, h1, h2, h3);
        *(short4*)(w_lo + dst) = make_short4(l0, l1, l2, l3);
    }
}

// ---------------------------------------------------------------------------
// Kernel 1 v4 (unchanged from round 9): 256-thread blocks, M=64, 2 blocks/CU.
__global__ __launch_bounds__(256, 2) void conv_mfma(
    const float* __restrict__ x,      // [NIMG,3,32,32]
    const short* __restrict__ w_hi,   // packed B-fragments
    const short* __restrict__ w_lo,
    short* __restrict__ fh,           // [NIMG][640] bf16 hi
    short* __restrict__ fl)           // [NIMG][640] bf16 lo
{
    __shared__ short Ah[64 * AS];             // 25.6 KB
    __shared__ short Al[64 * AS];             // 25.6 KB
    __shared__ float ssq_part[4][64];         // 1 KB
    __shared__ float inv_s[64];
    __shared__ float pooled_s[4 * CCH];       // 10.2 KB
    __shared__ float rn_part[4];
    __shared__ float invc_s[4];

    const int t = threadIdx.x;
    const int blk = blockIdx.x;

    // ---- load 4 images, rearrange to A[row=img*16+pos][k], split hi/lo
    {
        const float4* xp = (const float4*)(x + (size_t)blk * 4 * 3072);
#pragma unroll
        for (int i = 0; i < 12; i++) {
            int f = t + i * 256;              // 0..3071 float4s
            int img = f / 768;
            int rem = f - img * 768;
            int ci = rem >> 8;
            int rem2 = rem & 255;
            int h = rem2 >> 3;
            int w4 = (rem2 & 7) << 2;
            int s = ((h >> 3) << 2) + (w4 >> 3);
            int k0 = (ci << 6) + ((h & 7) << 3) + (w4 & 7);
            int row = (img << 4) + s;
            float4 v = xp[f];
            short h0, h1, h2, h3, l0, l1, l2, l3;
            split_bf16(v.x, h0, l0);
            split_bf16(v.y, h1, l1);
            split_bf16(v.z, h2, l2);
            split_bf16(v.w, h3, l3);
            *(short4*)&Ah[row * AS + k0] = make_short4(h0, h1, h2, h3);
            *(short4*)&Al[row * AS + k0] = make_short4(l0, l1, l2, l3);
        }
    }
    __syncthreads();

    const int wv = t >> 6;       // wave 0..3
    const int l  = t & 63;
    const int ln = l & 31;       // MFMA col lane
    const int hh = l >> 5;       // k-half

    f32x16 acc[10];              // acc[i*2 + mt]
#pragma unroll
    for (int j = 0; j < 10; j++)
#pragma unroll
        for (int r = 0; r < 16; r++) acc[j][r] = 0.f;

    const bf16x8* BH = (const bf16x8*)w_hi + (size_t)(wv * 5) * (NKS * 64) + l;
    const bf16x8* BL = (const bf16x8*)w_lo + (size_t)(wv * 5) * (NKS * 64) + l;
    const int abase = ln * AS + hh * 8;

    // K-loop: flat p = ks*5 + i (ks-outer so A is read once per ks).
    {
        bf16x8 cbh = BH[0], cbl = BL[0];      // (ks=0, i=0)
        bf16x8 aH0, aL0, aH1, aL1;
#pragma unroll
        for (int p = 0; p < 60; p++) {
            const int ks = p / 5;
            const int i  = p % 5;
            bf16x8 bh = cbh, bl = cbl;
            if (p + 1 < 60) {
                const int pn = p + 1;
                const int off = ((pn % 5) * NKS + pn / 5) * 64;
                cbh = BH[off];
                cbl = BL[off];
            }
            if (i == 0) {
                aH0 = *(const bf16x8*)&Ah[abase + ks * 16];
                aL0 = *(const bf16x8*)&Al[abase + ks * 16];
                aH1 = *(const bf16x8*)&Ah[abase + 32 * AS + ks * 16];
                aL1 = *(const bf16x8*)&Al[abase + 32 * AS + ks * 16];
            }
            acc[i * 2 + 0] = __builtin_amdgcn_mfma_f32_32x32x16_bf16(aH0, bh, acc[i * 2 + 0], 0, 0, 0);
            acc[i * 2 + 0] = __builtin_amdgcn_mfma_f32_32x32x16_bf16(aL0, bh, acc[i * 2 + 0], 0, 0, 0);
            acc[i * 2 + 0] = __builtin_amdgcn_mfma_f32_32x32x16_bf16(aH0, bl, acc[i * 2 + 0], 0, 0, 0);
            acc[i * 2 + 1] = __builtin_amdgcn_mfma_f32_32x32x16_bf16(aH1, bh, acc[i * 2 + 1], 0, 0, 0);
            acc[i * 2 + 1] = __builtin_amdgcn_mfma_f32_32x32x16_bf16(aL1, bh, acc[i * 2 + 1], 0, 0, 0);
            acc[i * 2 + 1] = __builtin_amdgcn_mfma_f32_32x32x16_bf16(aH1, bl, acc[i * 2 + 1], 0, 0, 0);
        }
    }

    // ---- ssq per row. C/D layout (32x32): col=ln, rl=(r&3)+8*(r>>2)+4*hh.
    {
        float rs0[16], rs1[16];
#pragma unroll
        for (int r = 0; r < 16; r++) { rs0[r] = 0.f; rs1[r] = 0.f; }
#pragma unroll
        for (int i = 0; i < 5; i++) {
#pragma unroll
            for (int r = 0; r < 16; r++) {
                rs0[r] += acc[i * 2 + 0][r] * acc[i * 2 + 0][r];
                rs1[r] += acc[i * 2 + 1][r] * acc[i * 2 + 1][r];
            }
        }
#pragma unroll
        for (int r = 0; r < 16; r++) {
            float v0 = rs0[r], v1 = rs1[r];
            v0 += __shfl_xor(v0, 1);  v1 += __shfl_xor(v1, 1);
            v0 += __shfl_xor(v0, 2);  v1 += __shfl_xor(v1, 2);
            v0 += __shfl_xor(v0, 4);  v1 += __shfl_xor(v1, 4);
            v0 += __shfl_xor(v0, 8);  v1 += __shfl_xor(v1, 8);
            v0 += __shfl_xor(v0, 16); v1 += __shfl_xor(v1, 16);
            if (ln == 0) {
                int rl = (r & 3) + ((r >> 2) << 3) + (hh << 2);
                ssq_part[wv][rl] = v0;
                ssq_part[wv][32 + rl] = v1;
            }
        }
    }
    __syncthreads();
    if (t < 64) {
        float s = ssq_part[0][t] + ssq_part[1][t] + ssq_part[2][t] + ssq_part[3][t];
        inv_s[t] = 1.f / fmaxf(sqrtf(s), 1e-12f);
    }
    __syncthreads();

    float iv0[16], iv1[16];
#pragma unroll
    for (int r = 0; r < 16; r++) {
        int rl = (r & 3) + ((r >> 2) << 3) + (hh << 2);
        iv0[r] = inv_s[rl];
        iv1[r] = inv_s[32 + rl];
    }

    // ---- pooled[img][c] = sum_pos inv[row]*C[row][c]
#pragma unroll
    for (int i = 0; i < 5; i++) {
        const int c = (wv * 5 + i) * 32 + ln;
#pragma unroll
        for (int mt = 0; mt < 2; mt++) {
            float p0 = 0.f, p1 = 0.f;
#pragma unroll
            for (int r = 0; r < 16; r++) {
                float pv = acc[i * 2 + mt][r] * ((mt == 0) ? iv0[r] : iv1[r]);
                if (r < 8) p0 += pv; else p1 += pv;
            }
            p0 += __shfl_xor(p0, 32);
            p1 += __shfl_xor(p1, 32);
            if (hh == 0) {
                pooled_s[(mt * 2 + 0) * CCH + c] = p0;
                pooled_s[(mt * 2 + 1) * CCH + c] = p1;
            }
        }
    }
    __syncthreads();

    // ---- per-image row L2-norm (wave wv handles image wv)
    {
        float s = 0.f;
#pragma unroll
        for (int j = 0; j < 10; j++) {
            float pv = pooled_s[wv * CCH + l + 64 * j];
            s += pv * pv;
        }
        s += __shfl_xor(s, 1);
        s += __shfl_xor(s, 2);
        s += __shfl_xor(s, 4);
        s += __shfl_xor(s, 8);
        s += __shfl_xor(s, 16);
        s += __shfl_xor(s, 32);
        if (l == 0) rn_part[wv] = s;
    }
    __syncthreads();
    if (t < 4)
        invc_s[t] = 1.f / fmaxf(sqrtf(rn_part[t]), 1e-12f);
    __syncthreads();
#pragma unroll
    for (int e0 = 0; e0 < 10; e0++) {
        int e = t + e0 * 256;                 // 0..2559
        int im = e / CCH;
        int c2 = e - im * CCH;
        float v = pooled_s[e] * invc_s[im];
        short vh, vl;
        split_bf16(v, vh, vl);
        size_t o = ((size_t)blk * 4 + im) * CCH + c2;
        fh[o] = vh;
        fl[o] = vl;
    }
}

// ---------------------------------------------------------------------------
// pack_s: build support-row MFMA A-fragments from fh/fl.
// Thread e = ((b*NSET+set)*QKS+ks)*64 + l: row48 = set*16+(l&15);
// if row48 < 45: m = row48/9, h = row48%9, src row = (b*80+m)*9+h,
// elems k = ks*32 + (l>>4)*8 + j. Else zeros. Output: 16B per thread/plane.
__global__ __launch_bounds__(256) void pack_s(
    const short* __restrict__ fh, const short* __restrict__ fl,
    short* __restrict__ sf_h, short* __restrict__ sf_l)
{
    int e = blockIdx.x * 256 + threadIdx.x;       // < 8*3*20*64 = 30720
    if (e >= BATCH * NSET * QKS * 64) return;
    int l = e & 63;
    int rest = e >> 6;
    int ks = rest % QKS;
    int rest2 = rest / QKS;
    int set = rest2 % NSET;
    int b = rest2 / NSET;
    int row48 = set * 16 + (l & 15);
    bf16x8 vh = {0,0,0,0,0,0,0,0}, vl = vh;
    if (row48 < WAY * NP) {
        int m = (row48 * 57) >> 9;                // /9
        int h = row48 - 9 * m;
        size_t src = ((size_t)(b * NSAMP + m) * NP + h) * CCH + ks * 32 + ((l >> 4) << 3);
        vh = *(const bf16x8*)&fh[src];
        vl = *(const bf16x8*)&fl[src];
    }
    *(bf16x8*)&sf_h[(size_t)e * 8] = vh;
    *(bf16x8*)&sf_l[(size_t)e * 8] = vl;
}

// ---------------------------------------------------------------------------
// Kernel 2 v4: per (b,n). A (supports) from packed fragments (coalesced),
// B (query) staged in LDS; 3 MFMA waves; 5 parallel greedy waves.
__global__ __launch_bounds__(320) void sim_mfma(
    const short* __restrict__ fh, const short* __restrict__ fl,
    const short* __restrict__ sf_h, const short* __restrict__ sf_l,
    float* __restrict__ out)                    // [8][75][5]
{
    __shared__ short qb_h[QKS * 64 * 8];        // 20.5 KB B-fragments (hi)
    __shared__ short qb_l[QKS * 64 * 8];        // 20.5 KB (lo)
    __shared__ float sims_s[WAY][84];

    const int n = blockIdx.x;
    const int b = blockIdx.y;
    const int t = threadIdx.x;

    // Stage Q B-fragments: lane l of frag ks holds Q_col(l&15)[ks*32+(l>>4)*8+j]
    for (int e = t; e < QKS * 64; e += 320) {
        int ks = e >> 6;
        int l2 = e & 63;
        int col = l2 & 15;
        int kb = ks * 32 + ((l2 >> 4) << 3);
        if (col < NP) {
            size_t qr = ((size_t)(b * NSAMP + WAY + n) * NP + col) * CCH + kb;
            *(bf16x8*)&qb_h[e * 8] = *(const bf16x8*)&fh[qr];
            *(bf16x8*)&qb_l[e * 8] = *(const bf16x8*)&fl[qr];
        } else {
            bf16x8 z = {0,0,0,0,0,0,0,0};
            *(bf16x8*)&qb_h[e * 8] = z;
            *(bf16x8*)&qb_l[e * 8] = z;
        }
    }
    __syncthreads();

    const int wv = t >> 6;
    const int l = t & 63;

    if (wv < NSET) {
        const bf16x8* AH = (const bf16x8*)sf_h + (size_t)((b * NSET + wv) * QKS) * 64 + l;
        const bf16x8* AL = (const bf16x8*)sf_l + (size_t)((b * NSET + wv) * QKS) * 64 + l;
        f32x4 acc = {0.f, 0.f, 0.f, 0.f};
#pragma unroll
        for (int ks = 0; ks < QKS; ks++) {
            bf16x8 ah = AH[ks * 64];
            bf16x8 al = AL[ks * 64];
            bf16x8 bh = *(const bf16x8*)&qb_h[(ks * 64 + l) * 8];
            bf16x8 bl = *(const bf16x8*)&qb_l[(ks * 64 + l) * 8];
            acc = __builtin_amdgcn_mfma_f32_16x16x32_bf16(ah, bh, acc, 0, 0, 0);
            acc = __builtin_amdgcn_mfma_f32_16x16x32_bf16(al, bh, acc, 0, 0, 0);
            acc = __builtin_amdgcn_mfma_f32_16x16x32_bf16(ah, bl, acc, 0, 0, 0);
        }
        // C/D: col = l&15, row = (l>>4)*4 + r
        int col = l & 15;
#pragma unroll
        for (int r = 0; r < 4; r++) {
            int sidx = wv * 16 + (l >> 4) * 4 + r;
            if (sidx < WAY * NP && col < NP) {
                int mm = (sidx * 57) >> 9;
                int hh2 = sidx - 9 * mm;
                sims_s[mm][hh2 * NP + col] = acc[r];
            }
        }
    }
    __syncthreads();

    // 5 waves, wave wv runs greedy for m = wv.
    {
        float v0 = sims_s[wv][l];
        float v1 = (l < 17) ? sims_s[wv][l + 64] : -3.0e38f;
        int d0r = l / NP, d0c = l - d0r * NP;
        int d1 = l + 64;
        int d1r = d1 / NP, d1c = d1 - d1r * NP;
        unsigned rm = 0x1FF, cm = 0x1FF;
        float total = 0.f, beta = 1.f;
        for (int it = 0; it < NP; it++) {
            float c0 = (((rm >> d0r) & 1u) && ((cm >> d0c) & 1u)) ? v0 : -3.0e38f;
            int i0 = l;
            float c1 = (l < 17 && ((rm >> d1r) & 1u) && ((cm >> d1c) & 1u)) ? v1 : -3.0e38f;
            if (c1 > c0) { c0 = c1; i0 = d1; }
#pragma unroll
            for (int off = 32; off >= 1; off >>= 1) {
                float ov = __shfl_xor(c0, off);
                int oi = __shfl_xor(i0, off);
                if (ov > c0 || (ov == c0 && oi < i0)) { c0 = ov; i0 = oi; }
            }
            total += fmaxf(c0, 0.f) * beta;
            beta *= 0.5f;
            int br = i0 / NP;
            int bc = i0 - br * NP;
            rm &= ~(1u << br);
            cm &= ~(1u << bc);
        }
        if (l == 0) out[((size_t)b * NQ + n) * WAY + wv] = total;
    }
}

extern "C" void kernel_launch(void* const* d_in, const int* in_sizes, int n_in,
                              void* d_out, int out_size, void* d_ws, size_t ws_size,
                              hipStream_t stream) {
    const float* data = (const float*)d_in[0];
    const float* conv_w = (const float*)d_in[1];

    short* fh   = (short*)d_ws;                      // 7,372,800 B
    short* fl   = fh + (size_t)NIMG * CCH;           // 7,372,800 B
    // Union region after fh/fl: w fragments (used by conv), then REUSED for
    // support fragments (pack_s runs after conv's last read of w — stream-
    // ordered, replay-safe since prep_w rewrites w each launch).
    short* w_hi = fl + (size_t)NIMG * CCH;           // 245,760 B
    short* w_lo = w_hi + (size_t)NFRAG * 8;          // 245,760 B
    short* sf_h = w_hi;                              // overlays w (dead after conv)
    short* sf_l = sf_h + (size_t)BATCH * NSET * QKS * 64 * 8;  // 491,520 B each

    prep_w_pack<<<(CCH * KLEN / 4 + 255) / 256, 256, 0, stream>>>(conv_w, w_hi, w_lo);
    conv_mfma<<<NIMG / 4, 256, 0, stream>>>(data, w_hi, w_lo, fh, fl);
    pack_s<<<(BATCH * NSET * QKS * 64 + 255) / 256, 256, 0, stream>>>(fh, fl, sf_h, sf_l);
    dim3 grid(NQ, BATCH);
    sim_mfma<<<grid, 320, 0, stream>>>(fh, fl, sf_h, sf_l, (float*)d_out);
}